// Round 1
// baseline (59.625 us; speedup 1.0000x reference)
//
#include <hip/hip_runtime.h>
#include <math.h>

#define H_BINS 61
#define HB2 (H_BINS * H_BINS)      // 3721
#define NPIX 22500                 // 150*150
#define NIMG 64
#define CHUNKS 4
#define PIX_PER_CHUNK (NPIX / CHUNKS)  // 5625

// EPS from reference, as float32 (reference adds python double to f32 array -> f32 add)
#define EPSF 2.2204e-16f
// EPS_BIN/2 = 6.4/61/2 computed in double, cast to f32 (matches jnp scalar cast)
#define HALFW ((float)(6.4 / 61.0 / 2.0))

// A[h] = -3.2f + h * delta, delta = (3.0951f - (-3.2f)) / 60.0f, all f32 rn ops
// (mirrors jnp.linspace: start + iota*delta in float32; rn intrinsics block FMA contraction)
__device__ __forceinline__ float bin_center(int h) {
    const float delta = __fdiv_rn(__fsub_rn(3.0951f, -3.2f), 60.0f);
    return __fadd_rn(-3.2f, __fmul_rn((float)h, delta));
}

// Find all bins h with |t - A[h]| <= HALFW (exact f32 predicate).
// Disjoint intervals => normally 0 or 1 match; we allow 2 for safety.
__device__ __forceinline__ int find_bins(float t, int* out) {
    const float inv_delta = 60.0f / 6.2951f;  // only used for the index ESTIMATE
    int h0 = (int)floorf(__fmul_rn(__fadd_rn(t, 3.2f), inv_delta) + 0.5f);
    int c = 0;
    #pragma unroll
    for (int dh = -1; dh <= 1; ++dh) {
        int h = h0 + dh;
        if (h < 0 || h >= H_BINS) continue;
        float a = bin_center(h);
        if (fabsf(__fsub_rn(t, a)) <= HALFW) {
            if (c < 2) out[c] = h;
            ++c;
        }
    }
    return c < 2 ? c : 2;
}

__global__ __launch_bounds__(256) void hist_kernel(const float* __restrict__ X,
                                                   float* __restrict__ out) {
    __shared__ float hist[3][HB2];
    const int b     = blockIdx.x / CHUNKS;
    const int chunk = blockIdx.x % CHUNKS;

    float* hflat = &hist[0][0];
    for (int i = threadIdx.x; i < 3 * HB2; i += 256) hflat[i] = 0.0f;
    __syncthreads();

    const float* Xb = X + (size_t)b * 3 * NPIX;
    const int n0 = chunk * PIX_PER_CHUNK;
    const int n1 = n0 + PIX_PER_CHUNK;

    for (int n = n0 + threadIdx.x; n < n1; n += 256) {
        float r  = Xb[n];
        float g  = Xb[NPIX + n];
        float bl = Xb[2 * NPIX + n];

        // Iy = sqrt(r*r + g*g + b*b) with f32 rn ops, sum order ((rr+gg)+bb) as in axis-reduce
        float iy = __fsqrt_rn(__fadd_rn(
            __fadd_rn(__fmul_rn(r, r), __fmul_rn(g, g)), __fmul_rn(bl, bl)));

        float l0 = logf(__fadd_rn(fabsf(r),  EPSF));
        float l1 = logf(__fadd_rn(fabsf(g),  EPSF));
        float l2 = logf(__fadd_rn(fabsf(bl), EPSF));

        // pairs: (i,u,v) = (0,1,2), (1,0,2), (2,0,1)
        float iu[3], iv[3];
        iu[0] = __fsub_rn(l0, l1);  iv[0] = __fsub_rn(l0, l2);
        iu[1] = __fsub_rn(l1, l0);  iv[1] = __fsub_rn(l1, l2);
        iu[2] = __fsub_rn(l2, l0);  iv[2] = __fsub_rn(l2, l1);

        #pragma unroll
        for (int p = 0; p < 3; ++p) {
            int bu[2], bv[2];
            int nu = find_bins(iu[p], bu);
            if (nu == 0) continue;
            int nv = find_bins(iv[p], bv);
            if (nv == 0) continue;
            for (int a = 0; a < nu; ++a)
                for (int c = 0; c < nv; ++c)
                    atomicAdd(&hist[p][bu[a] * H_BINS + bv[c]], iy);
        }
    }
    __syncthreads();

    float* ob = out + (size_t)b * 3 * HB2;
    for (int i = threadIdx.x; i < 3 * HB2; i += 256) {
        float v = hflat[i];
        if (v != 0.0f) atomicAdd(&ob[i], v);  // device-scope, cross-XCD safe
    }
}

__global__ __launch_bounds__(256) void finalize_kernel(float* __restrict__ out,
                                                       const float* __restrict__ C) {
    int idx = blockIdx.x * 256 + threadIdx.x;
    if (idx >= NIMG * 3 * HB2) return;
    int ch = (idx / HB2) % 3;
    float scale = __fdiv_rn(C[ch], 22500.0f);   // C[i]/N in f32, as reference
    out[idx] = __fmul_rn(__fsqrt_rn(out[idx]), scale);
}

extern "C" void kernel_launch(void* const* d_in, const int* in_sizes, int n_in,
                              void* d_out, int out_size, void* d_ws, size_t ws_size,
                              hipStream_t stream) {
    const float* X = (const float*)d_in[0];
    const float* C = (const float*)d_in[1];
    float* out = (float*)d_out;

    // replays don't re-zero d_out; we accumulate into it, so zero it each call
    hipMemsetAsync(out, 0, (size_t)out_size * sizeof(float), stream);

    hist_kernel<<<NIMG * CHUNKS, 256, 0, stream>>>(X, out);

    int total = NIMG * 3 * HB2;
    finalize_kernel<<<(total + 255) / 256, 256, 0, stream>>>(out, C);
}

// Round 2
// 50.745 us; speedup vs baseline: 1.1750x; 1.1750x over previous
//
#include <hip/hip_runtime.h>
#include <math.h>

#define H_BINS 61
#define HB2 (H_BINS * H_BINS)      // 3721
#define NPIX 22500                 // 150*150
#define NIMG 64
#define CHUNKS 9                   // 22500 / 9 = 2500 exactly
#define PIX_PER_CHUNK (NPIX / CHUNKS)

// EPS from reference, as float32
#define EPSF 2.2204e-16f
// EPS_BIN/2 = 6.4/61/2 computed in double, cast to f32 (matches jnp scalar cast)
#define HALFW ((float)(6.4 / 61.0 / 2.0))

// A[h] = -3.2f + h * delta, delta = (3.0951f - (-3.2f)) / 60.0f, all f32 rn ops
// (mirrors jnp.linspace in float32; rn intrinsics block FMA contraction)
__device__ __forceinline__ float bin_center(int h) {
    const float delta = __fdiv_rn(__fsub_rn(3.0951f, -3.2f), 60.0f);
    return __fadd_rn(-3.2f, __fmul_rn((float)h, delta));
}

// Find all bins h with |t - A[h]| <= HALFW (exact f32 predicate).
// Disjoint intervals => normally 0 or 1 match; we allow 2 for safety.
__device__ __forceinline__ int find_bins(float t, int* out) {
    const float inv_delta = 60.0f / 6.2951f;  // only used for the index ESTIMATE
    int h0 = (int)floorf(__fmul_rn(__fadd_rn(t, 3.2f), inv_delta) + 0.5f);
    int c = 0;
    #pragma unroll
    for (int dh = -1; dh <= 1; ++dh) {
        int h = h0 + dh;
        if (h < 0 || h >= H_BINS) continue;
        float a = bin_center(h);
        if (fabsf(__fsub_rn(t, a)) <= HALFW) {
            if (c < 2) out[c] = h;
            ++c;
        }
    }
    return c < 2 ? c : 2;
}

// One block = one (image, channel-pair, pixel-chunk). LDS = one 61x61 f32 hist
// (14.9 KB -> 8 blocks/CU, occupancy-capped at 32 waves/CU).
__global__ __launch_bounds__(256) void hist_kernel(const float* __restrict__ X,
                                                   float* __restrict__ out) {
    __shared__ float hist[HB2];
    // ordering: 3 consecutive blocks (p=0,1,2) share the same pixel chunk -> L2 reuse
    const int p     = blockIdx.x % 3;
    const int rest  = blockIdx.x / 3;
    const int chunk = rest % CHUNKS;
    const int b     = rest / CHUNKS;

    for (int i = threadIdx.x; i < HB2; i += 256) hist[i] = 0.0f;
    __syncthreads();

    const float* Xb = X + (size_t)b * 3 * NPIX;
    const int n0 = chunk * PIX_PER_CHUNK;
    const int n1 = n0 + PIX_PER_CHUNK;

    for (int n = n0 + threadIdx.x; n < n1; n += 256) {
        float r  = Xb[n];
        float g  = Xb[NPIX + n];
        float bl = Xb[2 * NPIX + n];

        // Iy = sqrt(r*r + g*g + b*b), f32 rn ops, sum order ((rr+gg)+bb)
        float iy = __fsqrt_rn(__fadd_rn(
            __fadd_rn(__fmul_rn(r, r), __fmul_rn(g, g)), __fmul_rn(bl, bl)));

        float l0 = logf(__fadd_rn(fabsf(r),  EPSF));
        float l1 = logf(__fadd_rn(fabsf(g),  EPSF));
        float l2 = logf(__fadd_rn(fabsf(bl), EPSF));

        // pairs: (i,u,v) = (0,1,2), (1,0,2), (2,0,1)
        float iu, iv;
        if (p == 0)      { iu = __fsub_rn(l0, l1); iv = __fsub_rn(l0, l2); }
        else if (p == 1) { iu = __fsub_rn(l1, l0); iv = __fsub_rn(l1, l2); }
        else             { iu = __fsub_rn(l2, l0); iv = __fsub_rn(l2, l1); }

        int bu[2], bv[2];
        int nu = find_bins(iu, bu);
        if (nu == 0) continue;
        int nv = find_bins(iv, bv);
        if (nv == 0) continue;
        for (int a = 0; a < nu; ++a)
            for (int c = 0; c < nv; ++c)
                atomicAdd(&hist[bu[a] * H_BINS + bv[c]], iy);
    }
    __syncthreads();

    float* ob = out + ((size_t)b * 3 + p) * HB2;
    for (int i = threadIdx.x; i < HB2; i += 256) {
        float v = hist[i];
        if (v != 0.0f) atomicAdd(&ob[i], v);  // device-scope, cross-XCD safe
    }
}

__global__ __launch_bounds__(256) void finalize_kernel(float* __restrict__ out,
                                                       const float* __restrict__ C) {
    int idx = blockIdx.x * 256 + threadIdx.x;
    if (idx >= NIMG * 3 * HB2) return;
    int ch = (idx / HB2) % 3;
    float scale = __fdiv_rn(C[ch], 22500.0f);   // C[i]/N in f32, as reference
    out[idx] = __fmul_rn(__fsqrt_rn(out[idx]), scale);
}

extern "C" void kernel_launch(void* const* d_in, const int* in_sizes, int n_in,
                              void* d_out, int out_size, void* d_ws, size_t ws_size,
                              hipStream_t stream) {
    const float* X = (const float*)d_in[0];
    const float* C = (const float*)d_in[1];
    float* out = (float*)d_out;

    // replays don't re-zero d_out; we accumulate into it, so zero it each call
    hipMemsetAsync(out, 0, (size_t)out_size * sizeof(float), stream);

    hist_kernel<<<NIMG * 3 * CHUNKS, 256, 0, stream>>>(X, out);

    int total = NIMG * 3 * HB2;
    finalize_kernel<<<(total + 255) / 256, 256, 0, stream>>>(out, C);
}